// Round 16
// baseline (41.370 us; speedup 1.0000x reference)
//
#include <hip/hip_runtime.h>

#define LAMB_COORD 5.0f
#define LAMB_NOOBJ 0.5f
#define GEPS 1e-7f

// gt/pred: (B=16384, C=30, H=7, W=7) fp32. Record = 1470 floats = 30ch x 49 cells.
// R12 structure, occupancy-doubled: 1024 blocks x 512 threads, RPB=16.
// __launch_bounds__(512,8): 8 waves/EU = 32 waves/CU = 4 blocks/CU (VGPR<=64).
// Phase A: direct stride-49 front gathers, ~2-trip cell loop (784 cells).
// Phase B: 16-trip unconditional class stream (tid<490), float2 + LDS app mask.

#define RPB   16
#define CELLS (RPB * 49)          // 784
#define CLS2R 490                 // float2 per record class region

__global__ __launch_bounds__(512, 8) void yolo_loss_kernel(
        const float* __restrict__ gt, const float* __restrict__ pred,
        float* __restrict__ out) {
    __shared__ float app[CELLS];  // 3136 B
    __shared__ float wsum[8];

    const int tid = threadIdx.x;
    const size_t rec0 = (size_t)blockIdx.x * RPB;

    float s = 0.0f;

    // ---- Phase A: front (channels 0..9), one cell per thread-iteration ----
    #pragma unroll 2
    for (int cell = tid; cell < CELLS; cell += 512) {
        const int rr = cell / 49;
        const int hw = cell - rr * 49;
        const float* __restrict__ g = gt   + (rec0 + rr) * 1470 + hw;
        const float* __restrict__ p = pred + (rec0 + rr) * 1470 + hw;

        float gv[10], pv[10];
        #pragma unroll
        for (int c = 0; c < 10; ++c) { gv[c] = g[c * 49]; pv[c] = p[c * 49]; }

        const float gx1 = gv[0], gy1 = gv[1];
        const float gx2 = gv[0] + gv[2], gy2 = gv[1] + gv[3];
        const float ga  = (gx2 - gx1) * (gy2 - gy1);

        float l[2];
        #pragma unroll
        for (int k = 0; k < 2; ++k) {
            const int o = k * 5;
            float px1 = pv[o + 0], py1 = pv[o + 1];
            float px2 = px1 + pv[o + 2], py2 = py1 + pv[o + 3];
            float ix1 = fmaxf(gx1, px1), iy1 = fmaxf(gy1, py1);
            float ix2 = fminf(gx2, px2), iy2 = fminf(gy2, py2);
            float inter = fmaxf(ix2 - ix1, 0.0f) * fmaxf(iy2 - iy1, 0.0f);
            float pa  = (px2 - px1) * (py2 - py1);
            float uni = ga + pa - inter;
            float iou = inter / (uni + GEPS);
            float cx1 = fminf(gx1, px1), cy1 = fminf(gy1, py1);
            float cx2 = fmaxf(gx2, px2), cy2 = fmaxf(gy2, py2);
            float enc = (cx2 - cx1) * (cy2 - cy1);
            l[k] = 1.0f - (iou - (enc - uni) / (enc + GEPS));
        }

        // jnp.argmax first-max tie-break: arg = 1 iff l2 > l1
        float r0, r1;
        if (l[1] > l[0]) { r0 = 0.0f;   r1 = gv[9]; }
        else             { r0 = gv[4];  r1 = 0.0f;  }
        app[cell] = fmaxf(r0, r1);

        float d;
        d = gv[0] - pv[0]; s += d * d * r0 * LAMB_COORD;
        d = gv[1] - pv[1]; s += d * d * r0 * LAMB_COORD;
        d = gv[5] - pv[5]; s += d * d * r1 * LAMB_COORD;
        d = gv[6] - pv[6]; s += d * d * r1 * LAMB_COORD;
        d = sqrtf(gv[2]) - sqrtf(pv[2]); s += d * d * r0 * LAMB_COORD;
        d = sqrtf(gv[3]) - sqrtf(pv[3]); s += d * d * r0 * LAMB_COORD;
        d = sqrtf(gv[7]) - sqrtf(pv[7]); s += d * d * r1 * LAMB_COORD;
        d = sqrtf(gv[8]) - sqrtf(pv[8]); s += d * d * r1 * LAMB_COORD;
        d = gv[4] - pv[4]; { float d2 = d * d; s += d2 * r0 + d2 * (1.0f - r0) * LAMB_NOOBJ; }
        d = gv[9] - pv[9]; { float d2 = d * d; s += d2 * r1 + d2 * (1.0f - r1) * LAMB_NOOBJ; }
    }
    __syncthreads();

    // ---- Phase B: class stream (channels 10..29), 16-trip record loop ----
    if (tid < CLS2R) {
        const int q = tid;
        int h0 = (2 * q) % 49;
        int h0n = (h0 == 48) ? 0 : h0 + 1;

        #pragma unroll 4
        for (int rr = 0; rr < RPB; ++rr) {
            const float2* __restrict__ gc = (const float2*)(gt   + (rec0 + rr) * 1470 + 490);
            const float2* __restrict__ pc = (const float2*)(pred + (rec0 + rr) * 1470 + 490);
            const int ab = rr * 49;

            float2 ga2 = gc[q];
            float2 pa2 = pc[q];
            float a0 = app[ab + h0];
            float a1 = app[ab + h0n];
            float d0 = ga2.x - pa2.x;
            float d1 = ga2.y - pa2.y;
            s += d0 * d0 * a0 + d1 * d1 * a1;
        }
    }

    // ---- Reduce: wave shuffle -> LDS -> one atomic per block ----
    #pragma unroll
    for (int off = 32; off > 0; off >>= 1)
        s += __shfl_down(s, off, 64);

    const int lane = tid & 63;
    const int wid  = tid >> 6;
    if (lane == 0) wsum[wid] = s;
    __syncthreads();
    if (tid == 0) {
        float b = 0.0f;
        #pragma unroll
        for (int w = 0; w < 8; ++w) b += wsum[w];
        atomicAdd(out, b);
    }
}

extern "C" void kernel_launch(void* const* d_in, const int* in_sizes, int n_in,
                              void* d_out, int out_size, void* d_ws, size_t ws_size,
                              hipStream_t stream) {
    const float* gt   = (const float*)d_in[0];
    const float* pred = (const float*)d_in[1];
    float* out = (float*)d_out;

    const int B = in_sizes[0] / 1470;    // 16384
    const int grid = B / RPB;            // 1024

    hipMemsetAsync(out, 0, sizeof(float) * out_size, stream);
    yolo_loss_kernel<<<grid, 512, 0, stream>>>(gt, pred, out);
}

// Round 17
// 40.264 us; speedup vs baseline: 1.0275x; 1.0275x over previous
//
#include <hip/hip_runtime.h>

#define LAMB_COORD 5.0f
#define LAMB_NOOBJ 0.5f
#define GEPS 1e-7f

// gt/pred: (B=16384, C=30, H=7, W=7) fp32. Record = 1470 floats = 30ch x 49 cells.
// 512 blocks x 512 threads, RPB=32 (R12 geometry). rec0 = 32*blockIdx (even).
// Phase A: byte-identical to R12 (direct stride-49 front gathers, ~3-trip loop).
// Phase B (NEW): float4 class stream (1 KB/wave-request, 2x R12's float2):
//   record parity decides alignment of the 980-float class region
//   (start byte 5880r+1960: odd r -> 16B-aligned, 245 float4 exactly;
//    even r -> 8-byte offset: float2 [e=0,1] + 244 float4 + float2 [e=978,979]).
//   Role split: tid 0..244 stream odd records, tid 256..499 even records,
//   tid 500 the leftover float2 pairs. 16 pair-trips; hw = e mod 49 is
//   loop-invariant per thread (computed once).

#define RPB   32
#define CELLS (RPB * 49)          // 1568

__global__ __launch_bounds__(512, 4) void yolo_loss_kernel(
        const float* __restrict__ gt, const float* __restrict__ pred,
        float* __restrict__ out) {
    __shared__ float app[CELLS];  // 6272 B
    __shared__ float wsum[8];

    const int tid = threadIdx.x;
    const size_t rec0 = (size_t)blockIdx.x * RPB;

    float s0 = 0.0f, s1 = 0.0f;

    // ---- Phase A: front (channels 0..9), one cell per thread-iteration ----
    #pragma unroll 2
    for (int cell = tid; cell < CELLS; cell += 512) {
        const int rr = cell / 49;
        const int hw = cell - rr * 49;
        const float* __restrict__ g = gt   + (rec0 + rr) * 1470 + hw;
        const float* __restrict__ p = pred + (rec0 + rr) * 1470 + hw;

        float gv[10], pv[10];
        #pragma unroll
        for (int c = 0; c < 10; ++c) { gv[c] = g[c * 49]; pv[c] = p[c * 49]; }

        const float gx1 = gv[0], gy1 = gv[1];
        const float gx2 = gv[0] + gv[2], gy2 = gv[1] + gv[3];
        const float ga  = (gx2 - gx1) * (gy2 - gy1);

        float l[2];
        #pragma unroll
        for (int k = 0; k < 2; ++k) {
            const int o = k * 5;
            float px1 = pv[o + 0], py1 = pv[o + 1];
            float px2 = px1 + pv[o + 2], py2 = py1 + pv[o + 3];
            float ix1 = fmaxf(gx1, px1), iy1 = fmaxf(gy1, py1);
            float ix2 = fminf(gx2, px2), iy2 = fminf(gy2, py2);
            float inter = fmaxf(ix2 - ix1, 0.0f) * fmaxf(iy2 - iy1, 0.0f);
            float pa  = (px2 - px1) * (py2 - py1);
            float uni = ga + pa - inter;
            float iou = inter / (uni + GEPS);
            float cx1 = fminf(gx1, px1), cy1 = fminf(gy1, py1);
            float cx2 = fmaxf(gx2, px2), cy2 = fmaxf(gy2, py2);
            float enc = (cx2 - cx1) * (cy2 - cy1);
            l[k] = 1.0f - (iou - (enc - uni) / (enc + GEPS));
        }

        // jnp.argmax first-max tie-break: arg = 1 iff l2 > l1
        float r0, r1;
        if (l[1] > l[0]) { r0 = 0.0f;   r1 = gv[9]; }
        else             { r0 = gv[4];  r1 = 0.0f;  }
        app[cell] = fmaxf(r0, r1);

        float t = 0.0f;
        float d;
        d = gv[0] - pv[0]; t += d * d * r0 * LAMB_COORD;
        d = gv[1] - pv[1]; t += d * d * r0 * LAMB_COORD;
        d = gv[5] - pv[5]; t += d * d * r1 * LAMB_COORD;
        d = gv[6] - pv[6]; t += d * d * r1 * LAMB_COORD;
        d = sqrtf(gv[2]) - sqrtf(pv[2]); t += d * d * r0 * LAMB_COORD;
        d = sqrtf(gv[3]) - sqrtf(pv[3]); t += d * d * r0 * LAMB_COORD;
        d = sqrtf(gv[7]) - sqrtf(pv[7]); t += d * d * r1 * LAMB_COORD;
        d = sqrtf(gv[8]) - sqrtf(pv[8]); t += d * d * r1 * LAMB_COORD;
        d = gv[4] - pv[4]; { float d2 = d * d; t += d2 * r0 + d2 * (1.0f - r0) * LAMB_NOOBJ; }
        d = gv[9] - pv[9]; { float d2 = d * d; t += d2 * r1 + d2 * (1.0f - r1) * LAMB_NOOBJ; }

        if ((cell >> 9) & 1) s1 += t; else s0 += t;
    }
    float s = s0 + s1;
    __syncthreads();

    // ---- Phase B: float4 class stream over 16 record-pairs ----
    if (tid < 245) {
        // odd records: 245 aligned float4, e0 = 4*tid
        const int e0 = 4 * tid;
        const int h0 = e0 % 49;
        const int h1 = (e0 + 1) % 49;
        const int h2 = (e0 + 2) % 49;
        const int h3 = (e0 + 3) % 49;
        #pragma unroll 4
        for (int pp = 0; pp < RPB / 2; ++pp) {
            const int rec = 2 * pp + 1;
            const float4* __restrict__ gc = (const float4*)(gt   + (rec0 + rec) * 1470 + 490);
            const float4* __restrict__ pc = (const float4*)(pred + (rec0 + rec) * 1470 + 490);
            const int ab = rec * 49;
            float4 g4 = gc[tid];
            float4 p4 = pc[tid];
            float d0 = g4.x - p4.x, d1 = g4.y - p4.y, d2 = g4.z - p4.z, d3 = g4.w - p4.w;
            s += d0 * d0 * app[ab + h0] + d1 * d1 * app[ab + h1]
               + d2 * d2 * app[ab + h2] + d3 * d3 * app[ab + h3];
        }
    } else if (tid >= 256 && tid < 500) {
        // even records: 244 float4 starting at e0 = 2 + 4*j
        const int j  = tid - 256;
        const int e0 = 2 + 4 * j;
        const int h0 = e0 % 49;
        const int h1 = (e0 + 1) % 49;
        const int h2 = (e0 + 2) % 49;
        const int h3 = (e0 + 3) % 49;
        #pragma unroll 4
        for (int pp = 0; pp < RPB / 2; ++pp) {
            const int rec = 2 * pp;
            const float* gb = gt   + (rec0 + rec) * 1470 + 490;
            const float* pb = pred + (rec0 + rec) * 1470 + 490;
            const float4* __restrict__ gc = (const float4*)(gb + 2);
            const float4* __restrict__ pc = (const float4*)(pb + 2);
            const int ab = rec * 49;
            float4 g4 = gc[j];
            float4 p4 = pc[j];
            float d0 = g4.x - p4.x, d1 = g4.y - p4.y, d2 = g4.z - p4.z, d3 = g4.w - p4.w;
            s += d0 * d0 * app[ab + h0] + d1 * d1 * app[ab + h1]
               + d2 * d2 * app[ab + h2] + d3 * d3 * app[ab + h3];
        }
    } else if (tid == 500) {
        // even records' leftovers: e = 0,1 and 978,979
        // hw: 0,1 and 978%49=47, 48
        #pragma unroll 4
        for (int pp = 0; pp < RPB / 2; ++pp) {
            const int rec = 2 * pp;
            const float* gb = gt   + (rec0 + rec) * 1470 + 490;
            const float* pb = pred + (rec0 + rec) * 1470 + 490;
            const int ab = rec * 49;
            float2 ga2 = *(const float2*)(gb);
            float2 pa2 = *(const float2*)(pb);
            float2 gb2 = *(const float2*)(gb + 978);
            float2 pb2 = *(const float2*)(pb + 978);
            float d0 = ga2.x - pa2.x, d1 = ga2.y - pa2.y;
            float d2 = gb2.x - pb2.x, d3 = gb2.y - pb2.y;
            s += d0 * d0 * app[ab + 0]  + d1 * d1 * app[ab + 1]
               + d2 * d2 * app[ab + 47] + d3 * d3 * app[ab + 48];
        }
    }

    // ---- Reduce: wave shuffle -> LDS -> one atomic per block ----
    #pragma unroll
    for (int off = 32; off > 0; off >>= 1)
        s += __shfl_down(s, off, 64);

    const int lane = tid & 63;
    const int wid  = tid >> 6;
    if (lane == 0) wsum[wid] = s;
    __syncthreads();
    if (tid == 0) {
        float b = 0.0f;
        #pragma unroll
        for (int w = 0; w < 8; ++w) b += wsum[w];
        atomicAdd(out, b);
    }
}

extern "C" void kernel_launch(void* const* d_in, const int* in_sizes, int n_in,
                              void* d_out, int out_size, void* d_ws, size_t ws_size,
                              hipStream_t stream) {
    const float* gt   = (const float*)d_in[0];
    const float* pred = (const float*)d_in[1];
    float* out = (float*)d_out;

    const int B = in_sizes[0] / 1470;    // 16384
    const int grid = B / RPB;            // 512

    hipMemsetAsync(out, 0, sizeof(float) * out_size, stream);
    yolo_loss_kernel<<<grid, 512, 0, stream>>>(gt, pred, out);
}